// Round 10
// baseline (57.058 us; speedup 1.0000x reference)
//
#include <hip/hip_runtime.h>
#include <math.h>

#define B_TOTAL 2048
#define I_DIM   128
#define O_DIM   128
#define GK      68
#define NKNOT   71
#define NT      8                    // n-tiles (128/16)
#define KS      3                    // k-steps (96/32)
#define FRAGS   (NT * KS)            // 24 fragments per i
#define SLICE_US (FRAGS * 512)       // 12288 ushorts = 24576 B per i
#define BT      128                  // b per block
#define BTILES  (B_TOTAL / BT)       // 16
#define RI      8                    // i per block
#define NR      (I_DIM / RI)         // 16 i-ranges
#define PART_FLOATS ((size_t)NR * B_TOTAL * O_DIM)      // 16 MB
#define WFRAG_OFF   (PART_FLOATS * 4)
#define WFRAG_BYTES ((size_t)I_DIM * SLICE_US * 2)      // 3 MB
#define WS_NEED     (WFRAG_OFF + WFRAG_BYTES)

typedef short  s16x8 __attribute__((ext_vector_type(8)));
typedef float  f32x4 __attribute__((ext_vector_type(4)));

__device__ __forceinline__ unsigned short f2bf(float f) {   // RNE
    unsigned u = __float_as_uint(f);
    return (unsigned short)((u + 0x7fffu + ((u >> 16) & 1u)) >> 16);
}

struct Coef { unsigned short h0, h1, h2, h3, h4; int g0; };

__device__ __forceinline__ Coef coef_eval(const float* __restrict__ x,
                                          const float* t_sh, int b, int i) {
    const float xv = x[(size_t)b * I_DIM + i];
    int ik = 3 + (int)floorf((xv + 1.0f) * 32.0f);
    ik = min(max(ik, 3), 66);
    while (ik < 66 && xv >= t_sh[ik + 1]) ++ik;
    while (ik > 3 && xv < t_sh[ik]) --ik;
    float l0, l1, l2, r0, r1, r2;
    float N0 = 1.0f, N1, N2, N3;
    l0 = xv - t_sh[ik];  r0 = t_sh[ik + 1] - xv;
    { float temp = N0 / (r0 + l0); N0 = r0 * temp; N1 = l0 * temp; }
    l1 = xv - t_sh[ik - 1];  r1 = t_sh[ik + 2] - xv;
    { float saved = 0.0f, temp;
      temp = N0 / (r0 + l1); N0 = saved + r0 * temp; saved = l1 * temp;
      temp = N1 / (r1 + l0); N1 = saved + r1 * temp; N2 = l0 * temp; }
    l2 = xv - t_sh[ik - 2];  r2 = t_sh[ik + 3] - xv;
    { float saved = 0.0f, temp;
      temp = N0 / (r0 + l2); N0 = saved + r0 * temp; saved = l2 * temp;
      temp = N1 / (r1 + l1); N1 = saved + r1 * temp; saved = l1 * temp;
      temp = N2 / (r2 + l0); N2 = saved + r2 * temp; N3 = l0 * temp; }
    const float silu = xv / (1.0f + expf(-xv));
    Coef c;
    c.h0 = f2bf(N0); c.h1 = f2bf(N1); c.h2 = f2bf(N2); c.h3 = f2bf(N3);
    c.h4 = f2bf(silu);
    c.g0 = ik - 3;
    return c;
}

// w f32 [GK][I][O] -> bf16 B-fragment-linear wf[i][frag][lane][8elems].
// frag = ntile*3 + kstep; lane elem j = W[kstep*32+(lane>>4)*8+j][ntile*16+(lane&15)]
// (rows >= GK zero). grid 768 = 128 i x 6; 256 thr = 4 waves, wave owns 1 frag.
__global__ __launch_bounds__(256)
void wcvt(const float* __restrict__ w, unsigned short* __restrict__ wf) {
    const int bid  = blockIdx.x;
    const int i    = bid / 6;
    const int wave = threadIdx.x >> 6;
    const int lane = threadIdx.x & 63;
    const int f    = (bid % 6) * 4 + wave;      // 0..23
    const int nt   = f / 3;
    const int ks   = f % 3;
    const int o    = nt * 16 + (lane & 15);
    const int kb   = ks * 32 + ((lane >> 4) << 3);

    unsigned short v[8];
    #pragma unroll
    for (int j = 0; j < 8; ++j) {
        const int k = kb + j;
        float s = 0.0f;
        if (k < GK) s = w[(size_t)k * (I_DIM * O_DIM) + (size_t)i * O_DIM + o];
        v[j] = f2bf(s);
    }
    uint4 st;
    st.x = (unsigned)v[0] | ((unsigned)v[1] << 16);
    st.y = (unsigned)v[2] | ((unsigned)v[3] << 16);
    st.z = (unsigned)v[4] | ((unsigned)v[5] << 16);
    st.w = (unsigned)v[6] | ((unsigned)v[7] << 16);
    *(uint4*)(wf + (size_t)i * SLICE_US + f * 512 + lane * 8) = st;
}

// grid = 16 btiles x 16 iranges = 256 blocks, 512 thr (8 waves).
// wave: wm = wave>>1 owns m-tiles {2wm, 2wm+1} (rows b0+32wm+{0..31});
//       wn = wave&1 owns n-tiles {4wn..4wn+3}.
// Per i: stage 24KB fragment slice (double-buffered global_load_lds);
// A-frags built in-reg from bf16 coefs (lane row = lane&15);
// 12 ds_read_b128 B-frags + 24 MFMA per wave per i.
__global__ __launch_bounds__(512, 2)
void flashkan_mfma(const float* __restrict__ x,
                   const unsigned short* __restrict__ wf,
                   const float* __restrict__ t,
                   float* __restrict__ part) {
    __shared__ __align__(16) unsigned short sbuf[2][SLICE_US];  // 2 x 24KB
    __shared__ float t_sh[NKNOT];

    const int tid  = threadIdx.x;
    const int bid  = blockIdx.x;
    const int btile = bid >> 4;
    const int ir    = bid & 15;
    const int b0    = btile * BT;
    const int i0    = ir * RI;
    const int wave  = tid >> 6;
    const int lane  = tid & 63;
    const int wm    = wave >> 1;
    const int wn    = wave & 1;
    const int rowA  = b0 + wm * 32 + (lane & 15);        // m-tile 2wm
    const int rowB  = rowA + 16;                         // m-tile 2wm+1
    const int k0g   = (lane >> 4) << 3;                  // lane's k-subgroup

    if (tid < NKNOT) t_sh[tid] = t[tid];
    __syncthreads();

    auto stage = [&](int sel, int i_abs) {
        #pragma unroll
        for (int q = 0; q < 3; ++q) {
            const int c = q * 8 + wave;                  // 24 chunks
            const unsigned short* src = wf + (size_t)i_abs * SLICE_US + c * 512 + lane * 8;
            void* dstp = (void*)((char*)&sbuf[sel][0] + c * 1024);
            __builtin_amdgcn_global_load_lds(
                (const __attribute__((address_space(1))) void*)src,
                (__attribute__((address_space(3))) void*)dstp,
                16, 0, 0);
        }
    };

    f32x4 accA[4], accB[4];
    #pragma unroll
    for (int n = 0; n < 4; ++n) { accA[n] = (f32x4)0.0f; accB[n] = (f32x4)0.0f; }

    auto build_a = [&](const Coef& c, int ks) -> s16x8 {
        const int k0 = ks * 32 + k0g;
        s16x8 a;
        #pragma unroll
        for (int j = 0; j < 8; ++j) {
            const int dk = k0 + j - c.g0;
            const int k  = k0 + j;
            unsigned short v = 0;
            v = (dk == 0) ? c.h0 : v;
            v = (dk == 1) ? c.h1 : v;
            v = (dk == 2) ? c.h2 : v;
            v = (dk == 3) ? c.h3 : v;
            v = (k == 67) ? c.h4 : v;
            a[j] = (short)v;
        }
        return a;
    };

    auto compute = [&](int i_abs, const unsigned short* buf) {
        const Coef cA = coef_eval(x, t_sh, rowA, i_abs);
        const Coef cB = coef_eval(x, t_sh, rowB, i_abs);
        #pragma unroll
        for (int ks = 0; ks < KS; ++ks) {
            const s16x8 aA = build_a(cA, ks);
            const s16x8 aB = build_a(cB, ks);
            #pragma unroll
            for (int n = 0; n < 4; ++n) {
                const int nt = wn * 4 + n;
                const s16x8 bf = *(const s16x8*)((const char*)buf +
                                   ((nt * 3 + ks) << 10) + (lane << 4));
                accA[n] = __builtin_amdgcn_mfma_f32_16x16x32_bf16(aA, bf, accA[n], 0, 0, 0);
                accB[n] = __builtin_amdgcn_mfma_f32_16x16x32_bf16(aB, bf, accB[n], 0, 0, 0);
            }
        }
    };

    stage(0, i0);
    __syncthreads();

    for (int ii = 0; ii < RI; ii += 2) {
        stage(1, i0 + ii + 1);
        compute(i0 + ii, sbuf[0]);
        __syncthreads();
        if (ii + 2 < RI) stage(0, i0 + ii + 2);
        compute(i0 + ii + 1, sbuf[1]);
        __syncthreads();
    }

    // epilogue: D row=(lane>>4)*4+reg (m), col=lane&15 (n)
    float* pbase = part + (size_t)ir * (B_TOTAL * O_DIM);
    #pragma unroll
    for (int n = 0; n < 4; ++n) {
        const int o = (wn * 4 + n) * 16 + (lane & 15);
        #pragma unroll
        for (int r = 0; r < 4; ++r) {
            const int bA = b0 + wm * 32 + (lane >> 4) * 4 + r;
            pbase[(size_t)bA * O_DIM + o]        = accA[n][r];
            pbase[(size_t)(bA + 16) * O_DIM + o] = accB[n][r];
        }
    }
}

// out[b][o] = sum_ir part[ir][b][o]
__global__ __launch_bounds__(256)
void flashkan_reduce(const float* __restrict__ ws, float* __restrict__ out) {
    const int f = blockIdx.x * 256 + threadIdx.x;
    const float4* base = (const float4*)ws + f;
    float4 s = make_float4(0.0f, 0.0f, 0.0f, 0.0f);
    #pragma unroll
    for (int r2 = 0; r2 < NR; ++r2) {
        const float4 v = base[(size_t)r2 * (B_TOTAL * O_DIM / 4)];
        s.x += v.x; s.y += v.y; s.z += v.z; s.w += v.w;
    }
    ((float4*)out)[f] = s;
}

// Fallback: R9's direct f32 gather (no ws needed).
__device__ __forceinline__ float rdlanef(float v, int l) {
    return __int_as_float(__builtin_amdgcn_readlane(__float_as_int(v), l));
}
__global__ __launch_bounds__(256)
void flashkan_gather_f32(const float* __restrict__ x,
                         const float* __restrict__ w,
                         const float* __restrict__ t,
                         float* __restrict__ out) {
    __shared__ float t_sh[NKNOT];
    __shared__ float psum[4][O_DIM];
    const int tid  = threadIdx.x;
    const int b    = blockIdx.x;
    const int wave = tid >> 6;
    const int lane = tid & 63;
    const int l32  = lane & 31;
    if (tid < NKNOT) t_sh[tid] = t[tid];
    __syncthreads();
    float cf0, cf1, cf2, cf3, cf4; int cg;
    {
        const float xv = x[(size_t)b * I_DIM + wave * 32 + l32];
        int ik = 3 + (int)floorf((xv + 1.0f) * 32.0f);
        ik = min(max(ik, 3), 66);
        while (ik < 66 && xv >= t_sh[ik + 1]) ++ik;
        while (ik > 3 && xv < t_sh[ik]) --ik;
        float l0, l1, l2, r0, r1, r2;
        float N0 = 1.0f, N1, N2, N3;
        l0 = xv - t_sh[ik];  r0 = t_sh[ik + 1] - xv;
        { float temp = N0 / (r0 + l0); N0 = r0 * temp; N1 = l0 * temp; }
        l1 = xv - t_sh[ik - 1];  r1 = t_sh[ik + 2] - xv;
        { float saved = 0.0f, temp;
          temp = N0 / (r0 + l1); N0 = saved + r0 * temp; saved = l1 * temp;
          temp = N1 / (r1 + l0); N1 = saved + r1 * temp; N2 = l0 * temp; }
        l2 = xv - t_sh[ik - 2];  r2 = t_sh[ik + 3] - xv;
        { float saved = 0.0f, temp;
          temp = N0 / (r0 + l2); N0 = saved + r0 * temp; saved = l2 * temp;
          temp = N1 / (r1 + l1); N1 = saved + r1 * temp; saved = l1 * temp;
          temp = N2 / (r2 + l0); N2 = saved + r2 * temp; N3 = l0 * temp; }
        cf0 = N0; cf1 = N1; cf2 = N2; cf3 = N3;
        cf4 = xv / (1.0f + expf(-xv));
        cg  = ik - 3;
    }
    const int i_base = wave * 32;
    float ax = 0.0f, ay = 0.0f;
    #pragma unroll 8
    for (int k = 0; k < 32; ++k) {
        const float c0 = rdlanef(cf0, k), c1 = rdlanef(cf1, k);
        const float c2 = rdlanef(cf2, k), c3 = rdlanef(cf3, k);
        const float c4 = rdlanef(cf4, k);
        const int   g0 = __builtin_amdgcn_readlane(cg, k);
        const int i = i_base + k;
        const float2* base = (const float2*)(w + (size_t)i * O_DIM) + lane;
        const size_t rs = (size_t)I_DIM * O_DIM / 2;
        const float2 v0 = base[(size_t)g0 * rs];
        const float2 v1 = base[(size_t)(g0 + 1) * rs];
        const float2 v2 = base[(size_t)(g0 + 2) * rs];
        const float2 v3 = base[(size_t)(g0 + 3) * rs];
        const float2 v4 = base[(size_t)(GK - 1) * rs];
        ax += c0 * v0.x + c1 * v1.x + c2 * v2.x + c3 * v3.x + c4 * v4.x;
        ay += c0 * v0.y + c1 * v1.y + c2 * v2.y + c3 * v3.y + c4 * v4.y;
    }
    psum[wave][lane * 2]     = ax;
    psum[wave][lane * 2 + 1] = ay;
    __syncthreads();
    if (tid < O_DIM) {
        out[(size_t)b * O_DIM + tid] =
            psum[0][tid] + psum[1][tid] + psum[2][tid] + psum[3][tid];
    }
}

extern "C" void kernel_launch(void* const* d_in, const int* in_sizes, int n_in,
                              void* d_out, int out_size, void* d_ws, size_t ws_size,
                              hipStream_t stream) {
    const float* x = (const float*)d_in[0];
    const float* w = (const float*)d_in[1];
    const float* t = (const float*)d_in[2];
    float* out = (float*)d_out;

    if (ws_size >= WS_NEED) {
        float* part = (float*)d_ws;
        unsigned short* wfr = (unsigned short*)((char*)d_ws + WFRAG_OFF);
        wcvt<<<I_DIM * 6, 256, 0, stream>>>(w, wfr);
        flashkan_mfma<<<BTILES * NR, 512, 0, stream>>>(x, wfr, t, part);
        flashkan_reduce<<<B_TOTAL * O_DIM / 4 / 256, 256, 0, stream>>>(part, out);
    } else {
        flashkan_gather_f32<<<B_TOTAL, 256, 0, stream>>>(x, w, t, out);
    }
}

// Round 11
// 43.692 us; speedup vs baseline: 1.3059x; 1.3059x over previous
//
#include <hip/hip_runtime.h>
#include <math.h>

#define B_TOTAL 2048
#define I_DIM   128
#define O_DIM   128
#define GK      68                  // G + k rows
#define NKNOT   71
#define BT      32                  // b per block
#define BTILES  (B_TOTAL / BT)      // 64
#define RI      8                   // i per block
#define NR      (I_DIM / RI)        // 16
#define THREADS 512                 // 8 waves
#define SLICE_B 17408               // 68 rows * 256 B (bf16)
#define SLICE_US (SLICE_B / 2)
#define PART_FLOATS ((size_t)NR * B_TOTAL * O_DIM)   // 16 MB
#define WF_OFF   (PART_FLOATS * 4)
#define WF_BYTES ((size_t)I_DIM * SLICE_B)           // 2.23 MB
#define WS_NEED  (WF_OFF + WF_BYTES)                 // ~18.4 MB

__device__ __forceinline__ float rdlanef(float v, int sl) {
    return __int_as_float(__builtin_amdgcn_readlane(__float_as_int(v), sl));
}
__device__ __forceinline__ unsigned short f2bf(float f) {   // RNE
    unsigned u = __float_as_uint(f);
    return (unsigned short)((u + 0x7fffu + ((u >> 16) & 1u)) >> 16);
}
__device__ __forceinline__ float bflo(unsigned u) { return __uint_as_float(u << 16); }
__device__ __forceinline__ float bfhi(unsigned u) { return __uint_as_float(u & 0xffff0000u); }

__device__ __forceinline__ float sel4f(int q, float a, float b, float c, float d) {
    float r = (q == 1) ? b : a;
    r = (q == 2) ? c : r;
    r = (q == 3) ? d : r;
    return r;
}
__device__ __forceinline__ int sel4i(int q, int a, int b, int c, int d) {
    int r = (q == 1) ? b : a;
    r = (q == 2) ? c : r;
    r = (q == 3) ? d : r;
    return r;
}

// de Boor coefs (exact ref order) for one (b,i)
__device__ __forceinline__ void coef_eval(float xv, const float* t_sh,
                                          float& c0, float& c1, float& c2,
                                          float& c3, float& c4, int& g0) {
    int ik = 3 + (int)floorf((xv + 1.0f) * 32.0f);
    ik = min(max(ik, 3), 66);
    while (ik < 66 && xv >= t_sh[ik + 1]) ++ik;
    while (ik > 3 && xv < t_sh[ik]) --ik;
    float l0, l1, l2, r0, r1, r2;
    float N0 = 1.0f, N1, N2, N3;
    l0 = xv - t_sh[ik];  r0 = t_sh[ik + 1] - xv;
    { float temp = N0 / (r0 + l0); N0 = r0 * temp; N1 = l0 * temp; }
    l1 = xv - t_sh[ik - 1];  r1 = t_sh[ik + 2] - xv;
    { float saved = 0.0f, temp;
      temp = N0 / (r0 + l1); N0 = saved + r0 * temp; saved = l1 * temp;
      temp = N1 / (r1 + l0); N1 = saved + r1 * temp; N2 = l0 * temp; }
    l2 = xv - t_sh[ik - 2];  r2 = t_sh[ik + 3] - xv;
    { float saved = 0.0f, temp;
      temp = N0 / (r0 + l2); N0 = saved + r0 * temp; saved = l2 * temp;
      temp = N1 / (r1 + l1); N1 = saved + r1 * temp; saved = l1 * temp;
      temp = N2 / (r2 + l0); N2 = saved + r2 * temp; N3 = l0 * temp; }
    c0 = N0; c1 = N1; c2 = N2; c3 = N3;
    c4 = xv / (1.0f + expf(-xv));
    g0 = ik - 3;
}

// w f32 [GK][I][O] -> bf16 [I][68 rows x 256B], 16B-block j of row r stored
// at block position j ^ (r & 15) (bank-decorrelates the quad-row read;
// staging stays linear since the swizzle is baked into the global layout).
// 544 blocks x 256 thr; thread handles one 16B out-block (8 bf16).
__global__ __launch_bounds__(256)
void wcvt(const float* __restrict__ w, unsigned short* __restrict__ wf) {
    const int gblk = blockIdx.x * 256 + threadIdx.x;    // < 128*68*16
    const int i    = gblk / (GK * 16);
    const int rem  = gblk - i * (GK * 16);
    const int r    = rem >> 4;
    const int j    = rem & 15;
    const float* src = w + ((size_t)r * I_DIM + i) * O_DIM + j * 8;
    const float4 a = *(const float4*)src;
    const float4 b = *(const float4*)(src + 4);
    uint4 st;
    st.x = (unsigned)f2bf(a.x) | ((unsigned)f2bf(a.y) << 16);
    st.y = (unsigned)f2bf(a.z) | ((unsigned)f2bf(a.w) << 16);
    st.z = (unsigned)f2bf(b.x) | ((unsigned)f2bf(b.y) << 16);
    st.w = (unsigned)f2bf(b.z) | ((unsigned)f2bf(b.w) << 16);
    char* dst = (char*)wf + (size_t)i * SLICE_B + r * 256 + ((j ^ (r & 15)) << 4);
    *(uint4*)dst = st;
}

// grid = 64 b-tiles x 16 i-ranges = 1024 blocks (4/CU), 512 thr (8 waves).
// Wave serves 4 b's (quarter-waves). Per (4b, i): 4 quad-addressed
// ds_read_b128 (lane row = g0(quarter)+k... no: read k fetches row g0+k for
// EVERY quarter's own b) + 1 broadcast silu read. Lane accumulates the full
// 8-o result of its quarter's b (k-terms all pass through every lane).
// Coefs per-wave in lanes 0..31 (bw=(l>>3)&3, ii=l&7), distributed per
// compute via 24 readlane + cndmask-select by quarter.
template<bool USE_WS>
__global__ __launch_bounds__(THREADS, 6)
void flashkan_q(const float* __restrict__ x,
                const unsigned short* __restrict__ wf,
                const float* __restrict__ t,
                float* __restrict__ dst) {
    __shared__ __align__(16) char sbuf[2][SLICE_B];   // 34816 B
    __shared__ float t_sh[NKNOT];

    const int tid = threadIdx.x;
    const int bid = blockIdx.x;
    const int bt  = bid >> 4;       // 0..63
    const int ir  = bid & 15;       // 0..15
    const int b0  = bt * BT;
    const int i0  = ir * RI;
    const int wv  = tid >> 6;
    const int l   = tid & 63;
    const int q   = l >> 4;         // quarter -> which b
    const int l15 = l & 15;         // 16B-block index (8 o's)

    if (tid < NKNOT) t_sh[tid] = t[tid];
    __syncthreads();

    // ---- coef phase: lane (l&31) owns (bw=(l>>3)&3, ii=l&7); hi lanes dup ----
    float cf0, cf1, cf2, cf3, cf4;
    int   cg;
    {
        const int bw = (l >> 3) & 3;
        const int ii = l & 7;
        const float xv = x[(size_t)(b0 + wv * 4 + bw) * I_DIM + (i0 + ii)];
        coef_eval(xv, t_sh, cf0, cf1, cf2, cf3, cf4, cg);
    }

    // ---- staging: bf16 slice i -> sbuf[sel] (linear; swizzle pre-baked) ----
    auto stage = [&](int sel, int i_abs) {
        for (int c = wv; c < 17; c += 8) {              // wave-uniform loop
            const unsigned short* src = wf + (size_t)i_abs * SLICE_US + c * 512 + l * 8;
            void* dstp = (void*)(&sbuf[sel][0] + c * 1024);
            __builtin_amdgcn_global_load_lds(
                (const __attribute__((address_space(1))) void*)src,
                (__attribute__((address_space(3))) void*)dstp,
                16, 0, 0);
        }
    };

    float acc[8];
    #pragma unroll
    for (int e = 0; e < 8; ++e) acc[e] = 0.0f;

    const int silu_off = 67 * 256 + ((l15 ^ 3) << 4);   // row 67, swizzled

    auto compute = [&](int ii, const char* bufc) {
        const int o0 = ii, o1 = 8 | ii, o2 = 16 | ii, o3 = 24 | ii;
        const float c0 = sel4f(q, rdlanef(cf0,o0), rdlanef(cf0,o1), rdlanef(cf0,o2), rdlanef(cf0,o3));
        const float c1 = sel4f(q, rdlanef(cf1,o0), rdlanef(cf1,o1), rdlanef(cf1,o2), rdlanef(cf1,o3));
        const float c2 = sel4f(q, rdlanef(cf2,o0), rdlanef(cf2,o1), rdlanef(cf2,o2), rdlanef(cf2,o3));
        const float c3 = sel4f(q, rdlanef(cf3,o0), rdlanef(cf3,o1), rdlanef(cf3,o2), rdlanef(cf3,o3));
        const float c4 = sel4f(q, rdlanef(cf4,o0), rdlanef(cf4,o1), rdlanef(cf4,o2), rdlanef(cf4,o3));
        const int  vg0 = sel4i(q,
            __builtin_amdgcn_readlane(cg,o0), __builtin_amdgcn_readlane(cg,o1),
            __builtin_amdgcn_readlane(cg,o2), __builtin_amdgcn_readlane(cg,o3));
        const float cc[4] = {c0, c1, c2, c3};

        #pragma unroll
        for (int k = 0; k < 4; ++k) {
            const int row = vg0 + k;
            const int off = (row << 8) | ((l15 ^ (row & 15)) << 4);
            const uint4 u = *(const uint4*)(bufc + off);
            const float ck = cc[k];
            acc[0] += ck * bflo(u.x);  acc[1] += ck * bfhi(u.x);
            acc[2] += ck * bflo(u.y);  acc[3] += ck * bfhi(u.y);
            acc[4] += ck * bflo(u.z);  acc[5] += ck * bfhi(u.z);
            acc[6] += ck * bflo(u.w);  acc[7] += ck * bfhi(u.w);
        }
        const uint4 su = *(const uint4*)(bufc + silu_off);  // bcast across quarters
        acc[0] += c4 * bflo(su.x);  acc[1] += c4 * bfhi(su.x);
        acc[2] += c4 * bflo(su.y);  acc[3] += c4 * bfhi(su.y);
        acc[4] += c4 * bflo(su.z);  acc[5] += c4 * bfhi(su.z);
        acc[6] += c4 * bflo(su.w);  acc[7] += c4 * bfhi(su.w);
    };

    stage(0, i0);
    __syncthreads();                // slice 0 landed

    for (int iib = 0; iib < RI; iib += 2) {
        stage(1, i0 + iib + 1);
        compute(iib, (const char*)sbuf[0]);
        __syncthreads();
        if (iib + 2 < RI) stage(0, i0 + iib + 2);
        compute(iib + 1, (const char*)sbuf[1]);
        __syncthreads();
    }

    // ---- epilogue: lane holds full 8-o result of b = b0+wv*4+q ----
    const int b = b0 + wv * 4 + q;
    const float4 A = make_float4(acc[0], acc[1], acc[2], acc[3]);
    const float4 Bv = make_float4(acc[4], acc[5], acc[6], acc[7]);
    if (USE_WS) {
        float* dp = dst + ((size_t)ir * B_TOTAL + b) * O_DIM + l15 * 8;
        *(float4*)dp = A;
        *(float4*)(dp + 4) = Bv;
    } else {
        float* dp = dst + (size_t)b * O_DIM + l15 * 8;
        atomicAdd(dp,     A.x); atomicAdd(dp + 1, A.y);
        atomicAdd(dp + 2, A.z); atomicAdd(dp + 3, A.w);
        atomicAdd(dp + 4, Bv.x); atomicAdd(dp + 5, Bv.y);
        atomicAdd(dp + 6, Bv.z); atomicAdd(dp + 7, Bv.w);
    }
}

// out[b][o] = sum_r part[r][b][o]
__global__ __launch_bounds__(256)
void flashkan_reduce(const float* __restrict__ ws, float* __restrict__ out) {
    const int f = blockIdx.x * 256 + threadIdx.x;
    const float4* base = (const float4*)ws + f;
    float4 s = make_float4(0.0f, 0.0f, 0.0f, 0.0f);
    #pragma unroll
    for (int r2 = 0; r2 < NR; ++r2) {
        const float4 v = base[(size_t)r2 * (B_TOTAL * O_DIM / 4)];
        s.x += v.x; s.y += v.y; s.z += v.z; s.w += v.w;
    }
    ((float4*)out)[f] = s;
}

// Fallback: R9 direct f32 gather (no ws needed).
__global__ __launch_bounds__(256)
void flashkan_gather_f32(const float* __restrict__ x,
                         const float* __restrict__ w,
                         const float* __restrict__ t,
                         float* __restrict__ out) {
    __shared__ float t_sh[NKNOT];
    __shared__ float psum[4][O_DIM];
    const int tid  = threadIdx.x;
    const int b    = blockIdx.x;
    const int wave = tid >> 6;
    const int lane = tid & 63;
    const int l32  = lane & 31;
    if (tid < NKNOT) t_sh[tid] = t[tid];
    __syncthreads();
    float cf0, cf1, cf2, cf3, cf4; int cg;
    {
        const float xv = x[(size_t)b * I_DIM + wave * 32 + l32];
        coef_eval(xv, t_sh, cf0, cf1, cf2, cf3, cf4, cg);
    }
    const int i_base = wave * 32;
    float ax = 0.0f, ay = 0.0f;
    #pragma unroll 8
    for (int k = 0; k < 32; ++k) {
        const float c0 = rdlanef(cf0, k), c1 = rdlanef(cf1, k);
        const float c2 = rdlanef(cf2, k), c3 = rdlanef(cf3, k);
        const float c4 = rdlanef(cf4, k);
        const int   g0 = __builtin_amdgcn_readlane(cg, k);
        const int i = i_base + k;
        const float2* base = (const float2*)(w + (size_t)i * O_DIM) + lane;
        const size_t rs = (size_t)I_DIM * O_DIM / 2;
        const float2 v0 = base[(size_t)g0 * rs];
        const float2 v1 = base[(size_t)(g0 + 1) * rs];
        const float2 v2 = base[(size_t)(g0 + 2) * rs];
        const float2 v3 = base[(size_t)(g0 + 3) * rs];
        const float2 v4 = base[(size_t)(GK - 1) * rs];
        ax += c0 * v0.x + c1 * v1.x + c2 * v2.x + c3 * v3.x + c4 * v4.x;
        ay += c0 * v0.y + c1 * v1.y + c2 * v2.y + c3 * v3.y + c4 * v4.y;
    }
    psum[wave][lane * 2]     = ax;
    psum[wave][lane * 2 + 1] = ay;
    __syncthreads();
    if (tid < O_DIM) {
        out[(size_t)b * O_DIM + tid] =
            psum[0][tid] + psum[1][tid] + psum[2][tid] + psum[3][tid];
    }
}

extern "C" void kernel_launch(void* const* d_in, const int* in_sizes, int n_in,
                              void* d_out, int out_size, void* d_ws, size_t ws_size,
                              hipStream_t stream) {
    const float* x = (const float*)d_in[0];
    const float* w = (const float*)d_in[1];
    const float* t = (const float*)d_in[2];
    float* out = (float*)d_out;

    const int wcvt_blocks = I_DIM * GK * 16 / 256;      // 544

    if (ws_size >= WS_NEED) {
        float* part = (float*)d_ws;
        unsigned short* wfp = (unsigned short*)((char*)d_ws + WF_OFF);
        wcvt<<<wcvt_blocks, 256, 0, stream>>>(w, wfp);
        flashkan_q<true><<<BTILES * NR, THREADS, 0, stream>>>(x, wfp, t, part);
        flashkan_reduce<<<B_TOTAL * O_DIM / 4 / 256, 256, 0, stream>>>(part, out);
    } else if (ws_size >= WF_BYTES) {
        unsigned short* wfp = (unsigned short*)d_ws;
        hipMemsetAsync(out, 0, (size_t)out_size * sizeof(float), stream);
        wcvt<<<wcvt_blocks, 256, 0, stream>>>(w, wfp);
        flashkan_q<false><<<BTILES * NR, THREADS, 0, stream>>>(x, wfp, t, out);
    } else {
        flashkan_gather_f32<<<B_TOTAL, 256, 0, stream>>>(x, w, t, out);
    }
}